// Round 6
// baseline (61.241 us; speedup 1.0000x reference)
//
#include <hip/hip_runtime.h>
#include <hip/hip_cooperative_groups.h>

namespace cg = cooperative_groups;

#define NS 512
#define DM 512
#define NH 8
#define DH 64
#define NHDH 512
#define ATTN_SIZE (2 * NH * NS * NS)  // 4194304

#define SMEM_A 9216    // Ts[64][72] bf16
#define SMEM_B 26112   // As[32][136] + Bs[64][136] bf16
#define SMEM_C 36096   // Kt[256][66] + Qs[16][72] f16

typedef __attribute__((ext_vector_type(8))) short short8v;
typedef __attribute__((ext_vector_type(4))) float f32x4;
typedef _Float16 h2 __attribute__((ext_vector_type(2)));
typedef unsigned short ushort_t;

__device__ __forceinline__ ushort_t f2bf(float x) {
    unsigned u = __float_as_uint(x);
    u = (u + 0x7FFFu + ((u >> 16) & 1u)) >> 16;   // RNE
    return (ushort_t)u;
}

#if defined(__has_builtin)
#if __has_builtin(__builtin_amdgcn_fdot2)
#define HAVE_FDOT2 1
#endif
#endif

__device__ __forceinline__ float qdot2(unsigned w2, unsigned x2, float acc) {
#ifdef HAVE_FDOT2
    return __builtin_amdgcn_fdot2(__builtin_bit_cast(h2, w2),
                                  __builtin_bit_cast(h2, x2), acc, false);
#else
    h2 a = __builtin_bit_cast(h2, w2);
    h2 b = __builtin_bit_cast(h2, x2);
    return acc + (float)a[0] * (float)b[0] + (float)a[1] * (float)b[1];
#endif
}

__device__ __forceinline__ float dotabs(unsigned w2, unsigned q2, unsigned k2, float acc) {
    h2 s = __builtin_bit_cast(h2, q2) + __builtin_bit_cast(h2, k2);  // v_pk_add_f16
    unsigned a = __builtin_bit_cast(unsigned, s) & 0x7FFF7FFFu;      // packed |.|
    return qdot2(w2, a, acc);                                        // v_dot2_f32_f16
}

// ======================= Phase A: convert =======================
__device__ __forceinline__ void phaseA(int bid, int tid,
    const float* __restrict__ query, const float* __restrict__ Wq,
    const float* __restrict__ Wk,
    ushort_t* __restrict__ Xb, ushort_t* __restrict__ Wqt,
    ushort_t* __restrict__ Wkt, char* smem)
{
    if (bid >= 256) return;
    if (bid < 128) {
        const int base = bid * 4096 + tid * 16;
        float4 v0 = *(const float4*)(query + base);
        float4 v1 = *(const float4*)(query + base + 4);
        float4 v2 = *(const float4*)(query + base + 8);
        float4 v3 = *(const float4*)(query + base + 12);
        union { ushort_t us[8]; uint4 v; } p0, p1;
        p0.us[0] = f2bf(v0.x); p0.us[1] = f2bf(v0.y); p0.us[2] = f2bf(v0.z); p0.us[3] = f2bf(v0.w);
        p0.us[4] = f2bf(v1.x); p0.us[5] = f2bf(v1.y); p0.us[6] = f2bf(v1.z); p0.us[7] = f2bf(v1.w);
        p1.us[0] = f2bf(v2.x); p1.us[1] = f2bf(v2.y); p1.us[2] = f2bf(v2.z); p1.us[3] = f2bf(v2.w);
        p1.us[4] = f2bf(v3.x); p1.us[5] = f2bf(v3.y); p1.us[6] = f2bf(v3.z); p1.us[7] = f2bf(v3.w);
        *(uint4*)(Xb + base) = p0.v;
        *(uint4*)(Xb + base + 8) = p1.v;
    } else {
        ushort_t (*Ts)[72] = (ushort_t(*)[72])smem;
        const float* __restrict__ W = (bid < 192) ? Wq : Wk;
        ushort_t* __restrict__ Wt = (bid < 192) ? Wqt : Wkt;
        const int t  = (bid - 128) & 63;
        const int tr = t >> 3;
        const int tc = t & 7;
        {
            const int r  = tid >> 2;
            const int cq = tid & 3;
            const float* src = W + (size_t)(tr * 64 + r) * NHDH + tc * 64 + cq * 16;
            #pragma unroll
            for (int v = 0; v < 4; ++v) {
                float4 a = *(const float4*)(src + v * 4);
                Ts[cq * 16 + v * 4 + 0][r] = f2bf(a.x);
                Ts[cq * 16 + v * 4 + 1][r] = f2bf(a.y);
                Ts[cq * 16 + v * 4 + 2][r] = f2bf(a.z);
                Ts[cq * 16 + v * 4 + 3][r] = f2bf(a.w);
            }
        }
        __syncthreads();
        {
            const int c  = tid >> 2;
            const int kq = tid & 3;
            uint4 o0 = *(const uint4*)&Ts[c][kq * 16];
            uint4 o1 = *(const uint4*)&Ts[c][kq * 16 + 8];
            ushort_t* dst = Wt + (size_t)(tc * 64 + c) * DM + tr * 64 + kq * 16;
            *(uint4*)(dst) = o0;
            *(uint4*)(dst + 8) = o1;
        }
    }
}

// ======================= Phase B: MFMA projections =======================
// 512 blocks: bz = bid>>8 (q/k), h = bid&7, by = (bid>>3)&31 (32-row tile).
__device__ __forceinline__ void phaseB(int bid, int tid,
    const ushort_t* __restrict__ Xb, const ushort_t* __restrict__ Wqt,
    const ushort_t* __restrict__ Wkt,
    const float* __restrict__ bq, const float* __restrict__ bk,
    ushort_t* __restrict__ qh, ushort_t* __restrict__ kh,
    float* __restrict__ kout, char* smem)
{
    const int bz = bid >> 8;
    const int h  = bid & 7;
    const int by = (bid >> 3) & 31;
    const ushort_t* __restrict__ Wt = bz ? Wkt : Wqt;
    const float* __restrict__ bia = bz ? bk : bq;
    ushort_t* __restrict__ hout = bz ? kh : qh;

    ushort_t (*As)[136] = (ushort_t(*)[136])smem;                  // 32 rows
    ushort_t (*Bs)[136] = (ushort_t(*)[136])(smem + 32 * 136 * 2); // 64 rows

    const int lane = tid & 63;
    const int wid  = __builtin_amdgcn_readfirstlane(tid >> 6);
    const int wr   = wid >> 1, wc = wid & 1;
    const int l15  = lane & 15, l4 = lane >> 4;

    uint4 ra[2], rb[4];
    #pragma unroll
    for (int i = 0; i < 2; ++i) {
        int s = i * 256 + tid;
        ra[i] = *(const uint4*)(Xb + (size_t)(by * 32 + (s >> 4)) * DM + (s & 15) * 8);
    }
    #pragma unroll
    for (int i = 0; i < 4; ++i) {
        int s = i * 256 + tid;
        rb[i] = *(const uint4*)(Wt + (size_t)(h * 64 + (s >> 4)) * DM + (s & 15) * 8);
    }

    f32x4 acc[2];
    acc[0] = (f32x4){0.f, 0.f, 0.f, 0.f};
    acc[1] = (f32x4){0.f, 0.f, 0.f, 0.f};

    for (int kc = 0; kc < 4; ++kc) {
        __syncthreads();
        #pragma unroll
        for (int i = 0; i < 2; ++i) {
            int s = i * 256 + tid;
            *(uint4*)&As[s >> 4][(s & 15) * 8] = ra[i];
        }
        #pragma unroll
        for (int i = 0; i < 4; ++i) {
            int s = i * 256 + tid;
            *(uint4*)&Bs[s >> 4][(s & 15) * 8] = rb[i];
        }
        __syncthreads();
        if (kc < 3) {
            #pragma unroll
            for (int i = 0; i < 2; ++i) {
                int s = i * 256 + tid;
                ra[i] = *(const uint4*)(Xb + (size_t)(by * 32 + (s >> 4)) * DM + (kc + 1) * 128 + (s & 15) * 8);
            }
            #pragma unroll
            for (int i = 0; i < 4; ++i) {
                int s = i * 256 + tid;
                rb[i] = *(const uint4*)(Wt + (size_t)(h * 64 + (s >> 4)) * DM + (kc + 1) * 128 + (s & 15) * 8);
            }
        }
        #pragma unroll
        for (int ks = 0; ks < 4; ++ks) {
            short8v a0 = *(const short8v*)&As[wr * 16 + l15      ][ks * 32 + l4 * 8];
            short8v b0 = *(const short8v*)&Bs[wc * 32 + l15      ][ks * 32 + l4 * 8];
            short8v b1 = *(const short8v*)&Bs[wc * 32 + 16 + l15 ][ks * 32 + l4 * 8];
            acc[0] = __builtin_amdgcn_mfma_f32_16x16x32_bf16(a0, b0, acc[0], 0, 0, 0);
            acc[1] = __builtin_amdgcn_mfma_f32_16x16x32_bf16(a0, b1, acc[1], 0, 0, 0);
        }
    }

    #pragma unroll
    for (int g = 0; g < 2; ++g) {
        const float bg = bia[h * 64 + wc * 32 + g * 16 + l15];
        #pragma unroll
        for (int j = 0; j < 4; ++j) {
            int rt = wr * 16 + l4 * 4 + j;
            int ct = wc * 32 + g * 16 + l15;
            int rg = by * 32 + rt;
            int ns_ = rg >> 1, b_ = rg & 1;
            size_t idx = ((size_t)(b_ * NH + h) * NS + ns_) * DH + ct;
            float vv = acc[g][j] + bg;
            if (bz) kout[idx] = vv;
            _Float16 hv = (_Float16)vv;
            hout[idx] = __builtin_bit_cast(ushort_t, hv);
        }
    }
}

// ======================= Phase C: attn =======================
// 512 blocks: bh = bid>>5, qt = bid&31 (16 q-rows). Wave wv owns 4 q-rows.
// Loop kk over two 256-row K halves; Kt[256][66] staged per half.
__device__ __forceinline__ void phaseC(int bid, int tid,
    const ushort_t* __restrict__ qh, const ushort_t* __restrict__ kh,
    const float* __restrict__ w, float* __restrict__ attn, char* smem)
{
    ushort_t (*Kt)[66] = (ushort_t(*)[66])smem;                    // 256 x 66
    ushort_t (*Qs)[72] = (ushort_t(*)[72])(smem + 256 * 66 * 2);   // 16 x 72

    const int lane = tid & 63;
    const int wv   = tid >> 6;
    const int bh   = bid >> 5;
    const int qt   = bid & 31;
    const int h    = bh & 7;

    if (tid < 128) {
        int row = tid >> 3, col = (tid & 7) * 8;
        *(uint4*)&Qs[row][col] =
            ((const uint4*)(qh + (size_t)bh * NS * DH + (size_t)qt * 16 * DH))[tid];
    }

    unsigned wp[32];
    const float* wrow = w + h * DH;
    #pragma unroll
    for (int i = 0; i < 16; ++i) {
        float4 v = *(const float4*)(wrow + i * 4);
        _Float16 a = (_Float16)v.x, b = (_Float16)v.y, c = (_Float16)v.z, d = (_Float16)v.w;
        unsigned lo = (unsigned)__builtin_bit_cast(ushort_t, a) |
                      ((unsigned)__builtin_bit_cast(ushort_t, b) << 16);
        unsigned hi = (unsigned)__builtin_bit_cast(ushort_t, c) |
                      ((unsigned)__builtin_bit_cast(ushort_t, d) << 16);
        wp[2 * i]     = __builtin_amdgcn_readfirstlane(lo);
        wp[2 * i + 1] = __builtin_amdgcn_readfirstlane(hi);
    }

    const uint4* ksrc = (const uint4*)(kh + (size_t)bh * NS * DH);
    float qd[4];

    for (int kk = 0; kk < 2; ++kk) {
        if (kk) __syncthreads();            // kk=0 readers done before restage
        #pragma unroll
        for (int i = 0; i < 8; ++i) {
            int f = i * 256 + tid;
            *(uint4*)&Kt[f >> 3][(f & 7) * 8] = ksrc[kk * 2048 + f];
        }
        __syncthreads();

        // lane's 4 k-rows (cols kk*256 + j*64 + lane); stride-66 rows -> 2-way
        __align__(16) unsigned kr[4][32];
        #pragma unroll
        for (int j = 0; j < 4; ++j) {
            const int row = j * 64 + lane;
            #pragma unroll
            for (int i = 0; i < 8; ++i)
                *(uint4*)&kr[j][i * 4] = *(const uint4*)&Kt[row][i * 8];
        }

        float kd0 = 0.f, kd1 = 0.f, kd2 = 0.f, kd3 = 0.f;
        #pragma unroll
        for (int p = 0; p < 32; ++p) {
            kd0 = qdot2(wp[p], kr[0][p], kd0);
            kd1 = qdot2(wp[p], kr[1][p], kd1);
            kd2 = qdot2(wp[p], kr[2][p], kd2);
            kd3 = qdot2(wp[p], kr[3][p], kd3);
        }

        float* obase = attn + (size_t)bh * NS * NS
                     + (size_t)(qt * 16 + wv * 4) * NS + kk * 256 + lane;

        #pragma unroll
        for (int r = 0; r < 4; ++r) {
            const int row = wv * 4 + r;
            __align__(16) unsigned q2a[32];
            #pragma unroll
            for (int i = 0; i < 8; ++i)
                *(uint4*)&q2a[i * 4] = *((const uint4*)&Qs[row][0] + i);

            if (kk == 0) {
                float qd0 = 0.f, qd1 = 0.f;
                #pragma unroll
                for (int p = 0; p < 16; ++p) {
                    qd0 = qdot2(wp[2 * p],     q2a[2 * p],     qd0);
                    qd1 = qdot2(wp[2 * p + 1], q2a[2 * p + 1], qd1);
                }
                qd[r] = qd0 + qd1;
            }

            float a0 = 0.f, a1 = 0.f, a2 = 0.f, a3 = 0.f;
            #pragma unroll
            for (int p = 0; p < 32; ++p) {
                const unsigned q2 = q2a[p], w2 = wp[p];
                a0 = dotabs(w2, q2, kr[0][p], a0);
                a1 = dotabs(w2, q2, kr[1][p], a1);
                a2 = dotabs(w2, q2, kr[2][p], a2);
                a3 = dotabs(w2, q2, kr[3][p], a3);
            }

            float* ob = obase + r * NS;
            ob[0]   = fmaf(0.495f, a0, 0.505f * (qd[r] + kd0));
            ob[64]  = fmaf(0.495f, a1, 0.505f * (qd[r] + kd1));
            ob[128] = fmaf(0.495f, a2, 0.505f * (qd[r] + kd2));
            ob[192] = fmaf(0.495f, a3, 0.505f * (qd[r] + kd3));
        }
    }
}

// ======================= kernels =======================
__global__ __launch_bounds__(256, 2) void fused_kernel(
    const float* __restrict__ query,
    const float* __restrict__ Wq, const float* __restrict__ bq,
    const float* __restrict__ Wk, const float* __restrict__ bk,
    const float* __restrict__ w,
    ushort_t* __restrict__ Xb, ushort_t* __restrict__ Wqt, ushort_t* __restrict__ Wkt,
    ushort_t* __restrict__ qh, ushort_t* __restrict__ kh,
    float* __restrict__ kout, float* __restrict__ attn)
{
    cg::grid_group grid = cg::this_grid();
    extern __shared__ __align__(16) char smem[];
    const int bid = blockIdx.x, tid = threadIdx.x;

    phaseA(bid, tid, query, Wq, Wk, Xb, Wqt, Wkt, smem);
    grid.sync();
    phaseB(bid, tid, Xb, Wqt, Wkt, bq, bk, qh, kh, kout, smem);
    grid.sync();
    phaseC(bid, tid, qh, kh, w, attn, smem);
}

__global__ __launch_bounds__(256) void kA(
    const float* __restrict__ query, const float* __restrict__ Wq,
    const float* __restrict__ Wk,
    ushort_t* __restrict__ Xb, ushort_t* __restrict__ Wqt, ushort_t* __restrict__ Wkt)
{
    extern __shared__ __align__(16) char smem[];
    phaseA(blockIdx.x, threadIdx.x, query, Wq, Wk, Xb, Wqt, Wkt, smem);
}

__global__ __launch_bounds__(256) void kB(
    const ushort_t* __restrict__ Xb, const ushort_t* __restrict__ Wqt,
    const ushort_t* __restrict__ Wkt,
    const float* __restrict__ bq, const float* __restrict__ bk,
    ushort_t* __restrict__ qh, ushort_t* __restrict__ kh, float* __restrict__ kout)
{
    extern __shared__ __align__(16) char smem[];
    phaseB(blockIdx.x, threadIdx.x, Xb, Wqt, Wkt, bq, bk, qh, kh, kout, smem);
}

__global__ __launch_bounds__(256, 2) void kC(
    const ushort_t* __restrict__ qh, const ushort_t* __restrict__ kh,
    const float* __restrict__ w, float* __restrict__ attn)
{
    extern __shared__ __align__(16) char smem[];
    phaseC(blockIdx.x, threadIdx.x, qh, kh, w, attn, smem);
}

extern "C" void kernel_launch(void* const* d_in, const int* in_sizes, int n_in,
                              void* d_out, int out_size, void* d_ws, size_t ws_size,
                              hipStream_t stream) {
    const float* query = (const float*)d_in[0];
    const float* Wq    = (const float*)d_in[1];
    const float* bq    = (const float*)d_in[2];
    const float* Wk    = (const float*)d_in[3];
    const float* bk    = (const float*)d_in[4];
    const float* w     = (const float*)d_in[5];

    float* attn = (float*)d_out;
    float* kout = (float*)d_out + ATTN_SIZE;     // k-proj f32 == output 2

    char* ws = (char*)d_ws;
    ushort_t* Xb  = (ushort_t*)(ws);                       // 1 MB bf16 query
    ushort_t* Wqt = (ushort_t*)(ws + (1u << 20));          // 0.5 MB bf16 Wq^T
    ushort_t* Wkt = (ushort_t*)(ws + (1u << 20) + DM * NHDH * 2);
    ushort_t* qh  = (ushort_t*)(ws + (2u << 20));          // 1 MB f16 q-proj
    ushort_t* kh  = (ushort_t*)(ws + (3u << 20));          // 1 MB f16 k-proj

    // capture-safe host queries -> deterministic path choice
    int dev = 0;
    (void)hipGetDevice(&dev);
    int nCU = 0, coopAttr = 0, maxB = 0;
    (void)hipDeviceGetAttribute(&nCU, hipDeviceAttributeMultiprocessorCount, dev);
    (void)hipDeviceGetAttribute(&coopAttr, hipDeviceAttributeCooperativeLaunch, dev);
    hipError_t oe = hipOccupancyMaxActiveBlocksPerMultiprocessor(
        &maxB, (const void*)fused_kernel, 256, (size_t)SMEM_C);

    bool coop = coopAttr && (oe == hipSuccess) && ((long)maxB * nCU >= 512);

    if (coop) {
        void* args[] = {(void*)&query, (void*)&Wq, (void*)&bq, (void*)&Wk, (void*)&bk,
                        (void*)&w, (void*)&Xb, (void*)&Wqt, (void*)&Wkt,
                        (void*)&qh, (void*)&kh, (void*)&kout, (void*)&attn};
        hipError_t le = hipLaunchCooperativeKernel((const void*)fused_kernel,
                                                   dim3(512), dim3(256),
                                                   args, SMEM_C, stream);
        if (le == hipSuccess) return;
    }

    // fallback: identical phases as three ordered kernels
    kA<<<256, 256, SMEM_A, stream>>>(query, Wq, Wk, Xb, Wqt, Wkt);
    kB<<<512, 256, SMEM_B, stream>>>(Xb, Wqt, Wkt, bq, bk, qh, kh, kout);
    kC<<<512, 256, SMEM_C, stream>>>(qh, kh, w, attn);
}

// Round 7
// 45.471 us; speedup vs baseline: 1.3468x; 1.3468x over previous
//
#include <hip/hip_runtime.h>

#define NS 512
#define DM 512
#define NH 8
#define DH 64
#define NHDH 512
#define ATTN_SIZE (2 * NH * NS * NS)  // 4194304

typedef __attribute__((ext_vector_type(8))) short short8v;
typedef __attribute__((ext_vector_type(4))) float f32x4;
typedef _Float16 h2 __attribute__((ext_vector_type(2)));
typedef unsigned short ushort_t;

__device__ __forceinline__ ushort_t f2bf(float x) {
    unsigned u = __float_as_uint(x);
    u = (u + 0x7FFFu + ((u >> 16) & 1u)) >> 16;   // RNE
    return (ushort_t)u;
}

#if defined(__has_builtin)
#if __has_builtin(__builtin_amdgcn_fdot2)
#define HAVE_FDOT2 1
#endif
#endif

__device__ __forceinline__ float qdot2(unsigned w2, unsigned x2, float acc) {
#ifdef HAVE_FDOT2
    return __builtin_amdgcn_fdot2(__builtin_bit_cast(h2, w2),
                                  __builtin_bit_cast(h2, x2), acc, false);
#else
    h2 a = __builtin_bit_cast(h2, w2);
    h2 b = __builtin_bit_cast(h2, x2);
    return acc + (float)a[0] * (float)b[0] + (float)a[1] * (float)b[1];
#endif
}

__device__ __forceinline__ float dotabs(unsigned w2, unsigned q2, unsigned k2, float acc) {
    h2 s = __builtin_bit_cast(h2, q2) + __builtin_bit_cast(h2, k2);  // v_pk_add_f16
    unsigned a = __builtin_bit_cast(unsigned, s) & 0x7FFF7FFFu;      // packed |.|
    return qdot2(w2, a, acc);                                        // v_dot2_f32_f16
}

// ---------------------------------------------------------------------------
// Pass 0: query f32 -> bf16; Wq/Wk f32 -> bf16 TRANSPOSED (Wt[col][k]).
// (verbatim from R4 - passing)
// ---------------------------------------------------------------------------
__global__ __launch_bounds__(256) void convert_kernel(
    const float* __restrict__ query,
    const float* __restrict__ Wq, const float* __restrict__ Wk,
    ushort_t* __restrict__ Xb,
    ushort_t* __restrict__ Wqt, ushort_t* __restrict__ Wkt)
{
    __shared__ __align__(16) ushort_t Ts[64][72];
    const int tid = threadIdx.x;
    const int blk = blockIdx.x;

    if (blk < 128) {
        const int base = blk * 4096 + tid * 16;
        float4 v0 = *(const float4*)(query + base);
        float4 v1 = *(const float4*)(query + base + 4);
        float4 v2 = *(const float4*)(query + base + 8);
        float4 v3 = *(const float4*)(query + base + 12);
        union { ushort_t us[8]; uint4 v; } p0, p1;
        p0.us[0] = f2bf(v0.x); p0.us[1] = f2bf(v0.y); p0.us[2] = f2bf(v0.z); p0.us[3] = f2bf(v0.w);
        p0.us[4] = f2bf(v1.x); p0.us[5] = f2bf(v1.y); p0.us[6] = f2bf(v1.z); p0.us[7] = f2bf(v1.w);
        p1.us[0] = f2bf(v2.x); p1.us[1] = f2bf(v2.y); p1.us[2] = f2bf(v2.z); p1.us[3] = f2bf(v2.w);
        p1.us[4] = f2bf(v3.x); p1.us[5] = f2bf(v3.y); p1.us[6] = f2bf(v3.z); p1.us[7] = f2bf(v3.w);
        *(uint4*)(Xb + base) = p0.v;
        *(uint4*)(Xb + base + 8) = p1.v;
        return;
    }

    const float* __restrict__ W = (blk < 192) ? Wq : Wk;
    ushort_t* __restrict__ Wt = (blk < 192) ? Wqt : Wkt;
    const int t  = (blk - 128) & 63;
    const int tr = t >> 3;
    const int tc = t & 7;

    {
        const int r  = tid >> 2;
        const int cq = tid & 3;
        const float* src = W + (size_t)(tr * 64 + r) * NHDH + tc * 64 + cq * 16;
        #pragma unroll
        for (int v = 0; v < 4; ++v) {
            float4 a = *(const float4*)(src + v * 4);
            Ts[cq * 16 + v * 4 + 0][r] = f2bf(a.x);
            Ts[cq * 16 + v * 4 + 1][r] = f2bf(a.y);
            Ts[cq * 16 + v * 4 + 2][r] = f2bf(a.z);
            Ts[cq * 16 + v * 4 + 3][r] = f2bf(a.w);
        }
    }
    __syncthreads();
    {
        const int c  = tid >> 2;
        const int kq = tid & 3;
        uint4 o0 = *(const uint4*)&Ts[c][kq * 16];
        uint4 o1 = *(const uint4*)&Ts[c][kq * 16 + 8];
        ushort_t* dst = Wt + (size_t)(tc * 64 + c) * DM + tr * 64 + kq * 16;
        *(uint4*)(dst) = o0;
        *(uint4*)(dst + 8) = o1;
    }
}

// ---------------------------------------------------------------------------
// Pass 1: MFMA bf16 GEMM -> qh/kh f16 [b,h,ns,dh] + kout f32 (output 2).
// (verbatim from R4 - passing)
// ---------------------------------------------------------------------------
__global__ __launch_bounds__(256) void proj_mfma(
    const ushort_t* __restrict__ Xb,
    const ushort_t* __restrict__ Wqt, const ushort_t* __restrict__ Wkt,
    const float* __restrict__ bq, const float* __restrict__ bk,
    ushort_t* __restrict__ qh, ushort_t* __restrict__ kh,
    float* __restrict__ kout)
{
    const int h  = blockIdx.x;
    const int by = blockIdx.y;
    const int bz = blockIdx.z;
    const ushort_t* __restrict__ Wt = bz ? Wkt : Wqt;
    const float* __restrict__ bia = bz ? bk : bq;
    ushort_t* __restrict__ hout = bz ? kh : qh;

    __shared__ __align__(16) ushort_t As[64][136];
    __shared__ __align__(16) ushort_t Bs[64][136];

    const int tid  = threadIdx.x;
    const int lane = tid & 63;
    const int w    = __builtin_amdgcn_readfirstlane(tid >> 6);
    const int wr   = w >> 1, wc = w & 1;
    const int l15  = lane & 15, l4 = lane >> 4;

    uint4 ra[4], rb[4];
    #pragma unroll
    for (int i = 0; i < 4; ++i) {
        int s = i * 256 + tid;
        int row = s >> 4, q = s & 15;
        ra[i] = *(const uint4*)(Xb + (size_t)(by * 64 + row) * DM + q * 8);
        rb[i] = *(const uint4*)(Wt + (size_t)(h * 64 + row) * DM + q * 8);
    }

    f32x4 acc[2][2];
    #pragma unroll
    for (int f = 0; f < 2; ++f)
        #pragma unroll
        for (int g = 0; g < 2; ++g) acc[f][g] = (f32x4){0.f, 0.f, 0.f, 0.f};

    for (int kc = 0; kc < 4; ++kc) {
        __syncthreads();
        #pragma unroll
        for (int i = 0; i < 4; ++i) {
            int s = i * 256 + tid;
            int row = s >> 4, q = s & 15;
            *(uint4*)&As[row][q * 8] = ra[i];
            *(uint4*)&Bs[row][q * 8] = rb[i];
        }
        __syncthreads();
        if (kc < 3) {
            #pragma unroll
            for (int i = 0; i < 4; ++i) {
                int s = i * 256 + tid;
                int row = s >> 4, q = s & 15;
                ra[i] = *(const uint4*)(Xb + (size_t)(by * 64 + row) * DM + (kc + 1) * 128 + q * 8);
                rb[i] = *(const uint4*)(Wt + (size_t)(h * 64 + row) * DM + (kc + 1) * 128 + q * 8);
            }
        }
        #pragma unroll
        for (int ks = 0; ks < 4; ++ks) {
            short8v a0 = *(const short8v*)&As[wr * 32 + l15     ][ks * 32 + l4 * 8];
            short8v a1 = *(const short8v*)&As[wr * 32 + 16 + l15][ks * 32 + l4 * 8];
            short8v b0 = *(const short8v*)&Bs[wc * 32 + l15     ][ks * 32 + l4 * 8];
            short8v b1 = *(const short8v*)&Bs[wc * 32 + 16 + l15][ks * 32 + l4 * 8];
            acc[0][0] = __builtin_amdgcn_mfma_f32_16x16x32_bf16(a0, b0, acc[0][0], 0, 0, 0);
            acc[0][1] = __builtin_amdgcn_mfma_f32_16x16x32_bf16(a0, b1, acc[0][1], 0, 0, 0);
            acc[1][0] = __builtin_amdgcn_mfma_f32_16x16x32_bf16(a1, b0, acc[1][0], 0, 0, 0);
            acc[1][1] = __builtin_amdgcn_mfma_f32_16x16x32_bf16(a1, b1, acc[1][1], 0, 0, 0);
        }
    }

    const float bias0 = bia[h * 64 + wc * 32 + l15];
    const float bias1 = bia[h * 64 + wc * 32 + 16 + l15];
    #pragma unroll
    for (int f = 0; f < 2; ++f)
        #pragma unroll
        for (int g = 0; g < 2; ++g) {
            float bg = g ? bias1 : bias0;
            #pragma unroll
            for (int j = 0; j < 4; ++j) {
                int rt = wr * 32 + f * 16 + l4 * 4 + j;
                int ct = wc * 32 + g * 16 + l15;
                int rg = by * 64 + rt;
                int ns_ = rg >> 1, b_ = rg & 1;
                size_t idx = ((size_t)(b_ * NH + h) * NS + ns_) * DH + ct;
                float vv = acc[f][g][j] + bg;
                if (bz) kout[idx] = vv;
                _Float16 hv = (_Float16)vv;
                hout[idx] = __builtin_bit_cast(ushort_t, hv);
            }
        }
}

// ---------------------------------------------------------------------------
// Pass 2 (attn3): attn[b,h,q,k] = 0.505*(Qd+Kd) + 0.495*sum_e w[e]*|q[e]+k[e]|
// 1024 blocks: kb = bid&3 (128 k-cols), bh = (bid>>2)&15, qt = bid>>6 (32 q).
// Wave = 8 q-rows x 128 k-cols. Lane owns 2 k-rows in regs (64 VGPR total).
// Q tile (32x64 f16, 4.6 KB) in LDS, uniform-broadcast reads. w in SGPRs.
// Designed for <=128 VGPR (no spill) -> 16 waves/CU = 4 waves/SIMD.
// ---------------------------------------------------------------------------
__global__ __launch_bounds__(256, 4) void attn3_kernel(
    const ushort_t* __restrict__ qh,   // [bh][ns][dh] f16
    const ushort_t* __restrict__ kh,   // [bh][ns][dh] f16
    const float* __restrict__ w,       // [8][64] f32
    float* __restrict__ attn)          // [b,h,q,k]
{
    __shared__ __align__(16) ushort_t Qs[32][72];  // 4.6 KB

    const int tid  = threadIdx.x;
    const int lane = tid & 63;
    const int wv   = tid >> 6;
    const int bid  = blockIdx.x;
    const int kb   = bid & 3;
    const int bh   = (bid >> 2) & 15;
    const int qt   = bid >> 6;         // 0..15
    const int h    = bh & 7;

    // ---- issue K loads first (2 rows/lane, 16 outstanding uint4) ----
    const int c0 = kb * 128 + lane;    // lane's first k-col
    const ushort_t* kb0 = kh + (size_t)bh * NS * DH + (size_t)c0 * DH;
    __align__(16) unsigned kr0[32], kr1[32];
    #pragma unroll
    for (int i = 0; i < 8; ++i)
        *(uint4*)&kr0[i * 4] = *(const uint4*)(kb0 + i * 8);
    #pragma unroll
    for (int i = 0; i < 8; ++i)
        *(uint4*)&kr1[i * 4] = *(const uint4*)(kb0 + 64 * DH + i * 8);

    // ---- stage Q tile (32 rows x 128 B = 4 KB, one coalesced pass) ----
    {
        const uint4* qsrc = (const uint4*)(qh + (size_t)bh * NS * DH + (size_t)qt * 32 * DH);
        int row = tid >> 3, col = (tid & 7) * 8;
        *(uint4*)&Qs[row][col] = qsrc[tid];
    }

    // ---- scoring weights -> f16 pairs in SGPRs ----
    unsigned wp[32];
    const float* wrow = w + h * DH;
    #pragma unroll
    for (int i = 0; i < 16; ++i) {
        float4 v = *(const float4*)(wrow + i * 4);
        _Float16 a = (_Float16)v.x, b = (_Float16)v.y, c = (_Float16)v.z, d = (_Float16)v.w;
        unsigned lo = (unsigned)__builtin_bit_cast(ushort_t, a) |
                      ((unsigned)__builtin_bit_cast(ushort_t, b) << 16);
        unsigned hi = (unsigned)__builtin_bit_cast(ushort_t, c) |
                      ((unsigned)__builtin_bit_cast(ushort_t, d) << 16);
        wp[2 * i]     = __builtin_amdgcn_readfirstlane(lo);
        wp[2 * i + 1] = __builtin_amdgcn_readfirstlane(hi);
    }

    // ---- Kdot for the lane's 2 k-rows ----
    float kd0 = 0.f, kd1 = 0.f;
    #pragma unroll
    for (int p = 0; p < 32; ++p) {
        kd0 = qdot2(wp[p], kr0[p], kd0);
        kd1 = qdot2(wp[p], kr1[p], kd1);
    }

    __syncthreads();

    float* obase = attn + (size_t)bh * NS * NS
                 + (size_t)(qt * 32 + wv * 8) * NS + kb * 128 + lane;

    #pragma unroll 2
    for (int r = 0; r < 8; ++r) {
        const int row = wv * 8 + r;
        __align__(16) unsigned q2a[32];
        #pragma unroll
        for (int i = 0; i < 8; ++i)
            *(uint4*)&q2a[i * 4] = *((const uint4*)&Qs[row][0] + i);

        float qd0 = 0.f, qd1 = 0.f;
        #pragma unroll
        for (int p = 0; p < 16; ++p) {
            qd0 = qdot2(wp[2 * p],     q2a[2 * p],     qd0);
            qd1 = qdot2(wp[2 * p + 1], q2a[2 * p + 1], qd1);
        }
        const float qd = qd0 + qd1;

        float a0 = 0.f, a1 = 0.f;
        #pragma unroll
        for (int p = 0; p < 32; ++p) {
            const unsigned q2 = q2a[p], w2 = wp[p];
            a0 = dotabs(w2, q2, kr0[p], a0);
            a1 = dotabs(w2, q2, kr1[p], a1);
        }

        float* ob = obase + r * NS;
        ob[0]  = fmaf(0.495f, a0, 0.505f * (qd + kd0));
        ob[64] = fmaf(0.495f, a1, 0.505f * (qd + kd1));
    }
}

extern "C" void kernel_launch(void* const* d_in, const int* in_sizes, int n_in,
                              void* d_out, int out_size, void* d_ws, size_t ws_size,
                              hipStream_t stream) {
    const float* query = (const float*)d_in[0];
    const float* Wq    = (const float*)d_in[1];
    const float* bq    = (const float*)d_in[2];
    const float* Wk    = (const float*)d_in[3];
    const float* bk    = (const float*)d_in[4];
    const float* w     = (const float*)d_in[5];

    float* attn = (float*)d_out;
    float* kout = (float*)d_out + ATTN_SIZE;     // k-proj f32 == output 2

    char* ws = (char*)d_ws;
    ushort_t* Xb  = (ushort_t*)(ws);                       // 1 MB bf16 query
    ushort_t* Wqt = (ushort_t*)(ws + (1u << 20));          // 0.5 MB bf16 Wq^T
    ushort_t* Wkt = (ushort_t*)(ws + (1u << 20) + DM * NHDH * 2);
    ushort_t* qh  = (ushort_t*)(ws + (2u << 20));          // 1 MB f16 q-proj
    ushort_t* kh  = (ushort_t*)(ws + (3u << 20));          // 1 MB f16 k-proj

    convert_kernel<<<256, 256, 0, stream>>>(query, Wq, Wk, Xb, Wqt, Wkt);
    proj_mfma<<<dim3(NH, 16, 2), 256, 0, stream>>>(Xb, Wqt, Wkt, bq, bk, qh, kh, kout);
    attn3_kernel<<<1024, 256, 0, stream>>>(qh, kh, w, attn);
}

// Round 9
// 33.612 us; speedup vs baseline: 1.8220x; 1.3528x over previous
//
#include <hip/hip_runtime.h>

#define NS 512
#define DM 512
#define NH 8
#define DH 64
#define NHDH 512
#define ATTN_SIZE (2 * NH * NS * NS)  // 4194304

typedef __attribute__((ext_vector_type(8))) _Float16 half8;
typedef __attribute__((ext_vector_type(4))) float f32x4;
typedef _Float16 h2 __attribute__((ext_vector_type(2)));
typedef unsigned short ushort_t;
typedef __attribute__((ext_vector_type(2))) unsigned uint2v;

#if defined(__has_builtin)
#if __has_builtin(__builtin_amdgcn_fdot2)
#define HAVE_FDOT2 1
#endif
#if __has_builtin(__builtin_amdgcn_cvt_pkrtz)
#define HAVE_PKRTZ 1
#endif
#endif

__device__ __forceinline__ unsigned pkh(float a, float b) {
#ifdef HAVE_PKRTZ
    auto r = __builtin_amdgcn_cvt_pkrtz(a, b);   // __fp16 ext_vector(2)
    return __builtin_bit_cast(unsigned, r);
#else
    h2 r; r[0] = (_Float16)a; r[1] = (_Float16)b;
    return __builtin_bit_cast(unsigned, r);
#endif
}

__device__ __forceinline__ float qdot2(unsigned w2, unsigned x2, float acc) {
#ifdef HAVE_FDOT2
    return __builtin_amdgcn_fdot2(__builtin_bit_cast(h2, w2),
                                  __builtin_bit_cast(h2, x2), acc, false);
#else
    h2 a = __builtin_bit_cast(h2, w2);
    h2 b = __builtin_bit_cast(h2, x2);
    return acc + (float)a[0] * (float)b[0] + (float)a[1] * (float)b[1];
#endif
}

__device__ __forceinline__ float dotabs(unsigned w2, unsigned q2, unsigned k2, float acc) {
    h2 s = __builtin_bit_cast(h2, q2) + __builtin_bit_cast(h2, k2);  // v_pk_add_f16
    unsigned a = __builtin_bit_cast(unsigned, s) & 0x7FFF7FFFu;      // packed |.|
    return qdot2(w2, a, acc);                                        // v_dot2_f32_f16
}

// ---------------------------------------------------------------------------
// Pass 1 (fused convert+proj): C = query @ W + b per matrix, f16 MFMA.
// Grid dim3(8,16,2): h = 64-col tile (one head), by = 64-row tile, bz = q/k.
// Staging converts f32->f16 in-register (v_cvt_pkrtz). W is transposed by the
// LOAD assignment: lane = column, 4 strided dword loads -> one b64 LDS write
// of k-contiguous halves. No separate convert kernel, no W^T workspace.
// Outputs qh/kh f16 [b,h,ns,dh] + kout f32 (reference output 2).
// ---------------------------------------------------------------------------
__global__ __launch_bounds__(256) void proj_fused(
    const float* __restrict__ query,
    const float* __restrict__ Wq, const float* __restrict__ bq,
    const float* __restrict__ Wk, const float* __restrict__ bk,
    ushort_t* __restrict__ qh, ushort_t* __restrict__ kh,
    float* __restrict__ kout)
{
    const int h  = blockIdx.x;
    const int by = blockIdx.y;
    const int bz = blockIdx.z;
    const float* __restrict__ W   = bz ? Wk : Wq;
    const float* __restrict__ bia = bz ? bk : bq;
    ushort_t* __restrict__ hout = bz ? kh : qh;

    __shared__ __align__(16) ushort_t As[64][136];
    __shared__ __align__(16) ushort_t Bs[64][136];

    const int tid  = threadIdx.x;
    const int lane = tid & 63;
    const int wv   = __builtin_amdgcn_readfirstlane(tid >> 6);
    const int wr   = wv >> 1, wc = wv & 1;
    const int l15  = lane & 15, l4 = lane >> 4;

    // ---- prologue: chunk 0 into registers ----
    float4 af[4][2];
    float  bf[8][4];
    #pragma unroll
    for (int i = 0; i < 4; ++i) {
        int s = i * 256 + tid;
        const float* src = query + (size_t)(by * 64 + (s >> 4)) * DM + (s & 15) * 8;
        af[i][0] = *(const float4*)(src);
        af[i][1] = *(const float4*)(src + 4);
    }
    #pragma unroll
    for (int p = 0; p < 8; ++p)
        #pragma unroll
        for (int j = 0; j < 4; ++j)
            bf[p][j] = W[(size_t)(p * 16 + (tid >> 6) * 4 + j) * NHDH + h * 64 + lane];

    f32x4 acc[2][2];
    #pragma unroll
    for (int f = 0; f < 2; ++f)
        #pragma unroll
        for (int g = 0; g < 2; ++g) acc[f][g] = (f32x4){0.f, 0.f, 0.f, 0.f};

    for (int kc = 0; kc < 4; ++kc) {
        __syncthreads();
        #pragma unroll
        for (int i = 0; i < 4; ++i) {
            int s = i * 256 + tid;
            uint4 pk;
            pk.x = pkh(af[i][0].x, af[i][0].y);
            pk.y = pkh(af[i][0].z, af[i][0].w);
            pk.z = pkh(af[i][1].x, af[i][1].y);
            pk.w = pkh(af[i][1].z, af[i][1].w);
            *(uint4*)&As[s >> 4][(s & 15) * 8] = pk;
        }
        #pragma unroll
        for (int p = 0; p < 8; ++p) {
            uint2v pk;
            pk.x = pkh(bf[p][0], bf[p][1]);
            pk.y = pkh(bf[p][2], bf[p][3]);
            *(uint2v*)&Bs[lane][p * 16 + (tid >> 6) * 4] = pk;
        }
        __syncthreads();
        if (kc < 3) {
            #pragma unroll
            for (int i = 0; i < 4; ++i) {
                int s = i * 256 + tid;
                const float* src = query + (size_t)(by * 64 + (s >> 4)) * DM
                                 + (kc + 1) * 128 + (s & 15) * 8;
                af[i][0] = *(const float4*)(src);
                af[i][1] = *(const float4*)(src + 4);
            }
            #pragma unroll
            for (int p = 0; p < 8; ++p)
                #pragma unroll
                for (int j = 0; j < 4; ++j)
                    bf[p][j] = W[(size_t)((kc + 1) * 128 + p * 16 + (tid >> 6) * 4 + j) * NHDH
                                 + h * 64 + lane];
        }
        #pragma unroll
        for (int ks = 0; ks < 4; ++ks) {
            half8 a0 = *(const half8*)&As[wr * 32 + l15     ][ks * 32 + l4 * 8];
            half8 a1 = *(const half8*)&As[wr * 32 + 16 + l15][ks * 32 + l4 * 8];
            half8 b0 = *(const half8*)&Bs[wc * 32 + l15     ][ks * 32 + l4 * 8];
            half8 b1 = *(const half8*)&Bs[wc * 32 + 16 + l15][ks * 32 + l4 * 8];
            acc[0][0] = __builtin_amdgcn_mfma_f32_16x16x32_f16(a0, b0, acc[0][0], 0, 0, 0);
            acc[0][1] = __builtin_amdgcn_mfma_f32_16x16x32_f16(a0, b1, acc[0][1], 0, 0, 0);
            acc[1][0] = __builtin_amdgcn_mfma_f32_16x16x32_f16(a1, b0, acc[1][0], 0, 0, 0);
            acc[1][1] = __builtin_amdgcn_mfma_f32_16x16x32_f16(a1, b1, acc[1][1], 0, 0, 0);
        }
    }

    const float bias0 = bia[h * 64 + wc * 32 + l15];
    const float bias1 = bia[h * 64 + wc * 32 + 16 + l15];
    #pragma unroll
    for (int f = 0; f < 2; ++f)
        #pragma unroll
        for (int g = 0; g < 2; ++g) {
            float bg = g ? bias1 : bias0;
            #pragma unroll
            for (int j = 0; j < 4; ++j) {
                int rt = wr * 32 + f * 16 + l4 * 4 + j;
                int ct = wc * 32 + g * 16 + l15;
                int rg = by * 64 + rt;
                int ns_ = rg >> 1, b_ = rg & 1;
                size_t idx = ((size_t)(b_ * NH + h) * NS + ns_) * DH + ct;
                float vv = acc[f][g][j] + bg;
                if (bz) kout[idx] = vv;
                _Float16 hv = (_Float16)vv;
                hout[idx] = __builtin_bit_cast(ushort_t, hv);
            }
        }
}

// ---------------------------------------------------------------------------
// Pass 2 (attn3, verbatim from R7 - passing):
// attn[b,h,q,k] = 0.505*(Qd+Kd) + 0.495*sum_e w[e]*|q[e]+k[e]|
// 1024 blocks: kb = bid&3 (128 k-cols), bh = (bid>>2)&15, qt = bid>>6.
// Wave = 8 q-rows x 128 k-cols; lane owns 2 k-rows in regs (64 VGPR).
// ---------------------------------------------------------------------------
__global__ __launch_bounds__(256, 4) void attn3_kernel(
    const ushort_t* __restrict__ qh,   // [bh][ns][dh] f16
    const ushort_t* __restrict__ kh,   // [bh][ns][dh] f16
    const float* __restrict__ w,       // [8][64] f32
    float* __restrict__ attn)          // [b,h,q,k]
{
    __shared__ __align__(16) ushort_t Qs[32][72];  // 4.6 KB

    const int tid  = threadIdx.x;
    const int lane = tid & 63;
    const int wv   = tid >> 6;
    const int bid  = blockIdx.x;
    const int kb   = bid & 3;
    const int bh   = (bid >> 2) & 15;
    const int qt   = bid >> 6;         // 0..15
    const int h    = bh & 7;

    // ---- issue K loads first (2 rows/lane, 16 outstanding uint4) ----
    const int c0 = kb * 128 + lane;    // lane's first k-col
    const ushort_t* kb0 = kh + (size_t)bh * NS * DH + (size_t)c0 * DH;
    __align__(16) unsigned kr0[32], kr1[32];
    #pragma unroll
    for (int i = 0; i < 8; ++i)
        *(uint4*)&kr0[i * 4] = *(const uint4*)(kb0 + i * 8);
    #pragma unroll
    for (int i = 0; i < 8; ++i)
        *(uint4*)&kr1[i * 4] = *(const uint4*)(kb0 + 64 * DH + i * 8);

    // ---- stage Q tile (32 rows x 128 B = 4 KB, one coalesced pass) ----
    {
        const uint4* qsrc = (const uint4*)(qh + (size_t)bh * NS * DH + (size_t)qt * 32 * DH);
        int row = tid >> 3, col = (tid & 7) * 8;
        *(uint4*)&Qs[row][col] = qsrc[tid];
    }

    // ---- scoring weights -> f16 pairs in SGPRs ----
    unsigned wp[32];
    const float* wrow = w + h * DH;
    #pragma unroll
    for (int i = 0; i < 16; ++i) {
        float4 v = *(const float4*)(wrow + i * 4);
        _Float16 a = (_Float16)v.x, b = (_Float16)v.y, c = (_Float16)v.z, d = (_Float16)v.w;
        unsigned lo = (unsigned)__builtin_bit_cast(ushort_t, a) |
                      ((unsigned)__builtin_bit_cast(ushort_t, b) << 16);
        unsigned hi = (unsigned)__builtin_bit_cast(ushort_t, c) |
                      ((unsigned)__builtin_bit_cast(ushort_t, d) << 16);
        wp[2 * i]     = __builtin_amdgcn_readfirstlane(lo);
        wp[2 * i + 1] = __builtin_amdgcn_readfirstlane(hi);
    }

    // ---- Kdot for the lane's 2 k-rows ----
    float kd0 = 0.f, kd1 = 0.f;
    #pragma unroll
    for (int p = 0; p < 32; ++p) {
        kd0 = qdot2(wp[p], kr0[p], kd0);
        kd1 = qdot2(wp[p], kr1[p], kd1);
    }

    __syncthreads();

    float* obase = attn + (size_t)bh * NS * NS
                 + (size_t)(qt * 32 + wv * 8) * NS + kb * 128 + lane;

    #pragma unroll 2
    for (int r = 0; r < 8; ++r) {
        const int row = wv * 8 + r;
        __align__(16) unsigned q2a[32];
        #pragma unroll
        for (int i = 0; i < 8; ++i)
            *(uint4*)&q2a[i * 4] = *((const uint4*)&Qs[row][0] + i);

        float qd0 = 0.f, qd1 = 0.f;
        #pragma unroll
        for (int p = 0; p < 16; ++p) {
            qd0 = qdot2(wp[2 * p],     q2a[2 * p],     qd0);
            qd1 = qdot2(wp[2 * p + 1], q2a[2 * p + 1], qd1);
        }
        const float qd = qd0 + qd1;

        float a0 = 0.f, a1 = 0.f;
        #pragma unroll
        for (int p = 0; p < 32; ++p) {
            const unsigned q2 = q2a[p], w2 = wp[p];
            a0 = dotabs(w2, q2, kr0[p], a0);
            a1 = dotabs(w2, q2, kr1[p], a1);
        }

        float* ob = obase + r * NS;
        ob[0]  = fmaf(0.495f, a0, 0.505f * (qd + kd0));
        ob[64] = fmaf(0.495f, a1, 0.505f * (qd + kd1));
    }
}

extern "C" void kernel_launch(void* const* d_in, const int* in_sizes, int n_in,
                              void* d_out, int out_size, void* d_ws, size_t ws_size,
                              hipStream_t stream) {
    const float* query = (const float*)d_in[0];
    const float* Wq    = (const float*)d_in[1];
    const float* bq    = (const float*)d_in[2];
    const float* Wk    = (const float*)d_in[3];
    const float* bk    = (const float*)d_in[4];
    const float* w     = (const float*)d_in[5];

    float* attn = (float*)d_out;
    float* kout = (float*)d_out + ATTN_SIZE;     // k-proj f32 == output 2

    char* ws = (char*)d_ws;
    ushort_t* qh = (ushort_t*)(ws);              // 1 MB f16 q-proj
    ushort_t* kh = (ushort_t*)(ws + (1u << 20)); // 1 MB f16 k-proj

    proj_fused<<<dim3(NH, 16, 2), 256, 0, stream>>>(query, Wq, bq, Wk, bk, qh, kh, kout);
    attn3_kernel<<<1024, 256, 0, stream>>>(qh, kh, w, attn);
}